// Round 1
// baseline (597.781 us; speedup 1.0000x reference)
//
#include <hip/hip_runtime.h>

#define THREADS 512
#define E_BLK 64   // edges per block-tile; 8 waves x 8 edges

// out[e] = relu(x @ W1 + b1) @ W2 + b2,  x = z[edge0[e]] * z[edge1[e]]
__global__ __launch_bounds__(THREADS, 2) void edge_mlp_f32(
    const float* __restrict__ z,
    const void* __restrict__ edge,   // int32 or int64, detected on device
    const float* __restrict__ W1,    // [128][128] row-major (in_ch x hid)
    const float* __restrict__ b1,    // [128]
    const float* __restrict__ W2,    // [128]
    const float* __restrict__ b2,    // [1]
    float* __restrict__ out,         // [nE]
    int nE)
{
    __shared__ float sW1[128 * 128];     // 64 KiB, row-major as given
    __shared__ float sB1[128];
    __shared__ float sW2[128];
    __shared__ float sX[E_BLK][128];     // 32 KiB
    __shared__ int   sI64;

    // ---- one-time staging: W1, b1, W2, index-width detection ----
    for (int k = threadIdx.x; k < 128 * 128 / 4; k += THREADS)
        ((float4*)sW1)[k] = ((const float4*)W1)[k];
    if (threadIdx.x < 128) {
        sB1[threadIdx.x] = b1[threadIdx.x];
        sW2[threadIdx.x] = W2[threadIdx.x];
    }
    if (threadIdx.x < 64) {  // wave 0: if all odd 32-bit words are 0 -> int64 indices
        unsigned int v = ((const unsigned int*)edge)[2 * threadIdx.x + 1];
        unsigned long long nz = __ballot(v != 0u);
        if (threadIdx.x == 0) sI64 = (nz == 0ull) ? 1 : 0;
    }
    const float bias2 = b2[0];
    __syncthreads();
    const int i64 = sI64;

    const int wave = threadIdx.x >> 6;   // 0..7
    const int lane = threadIdx.x & 63;

    const int nTiles = (nE + E_BLK - 1) / E_BLK;
    for (int tile = blockIdx.x; tile < nTiles; tile += gridDim.x) {
        const int e0 = tile * E_BLK;

        // ---- stage x = z[a] * z[b] for 64 edges; 8 threads per edge ----
        {
            const int e  = threadIdx.x >> 3;   // 0..63
            const int q  = threadIdx.x & 7;    // float4 slot
            const int ee = e0 + e;
            if (ee < nE) {
                long a, b;
                if (i64) {
                    const long long* p = (const long long*)edge;
                    a = (long)p[ee]; b = (long)p[nE + ee];
                } else {
                    const int* p = (const int*)edge;
                    a = p[ee]; b = p[nE + ee];
                }
                const float4* za = (const float4*)(z + a * 128);
                const float4* zb = (const float4*)(z + b * 128);
                float4* xd = (float4*)(&sX[e][0]);
                #pragma unroll
                for (int r = 0; r < 4; ++r) {
                    float4 pa = za[q + 8 * r];
                    float4 pb = zb[q + 8 * r];
                    float4 v;
                    v.x = pa.x * pb.x; v.y = pa.y * pb.y;
                    v.z = pa.z * pb.z; v.w = pa.w * pb.w;
                    xd[q + 8 * r] = v;
                }
            }
        }
        __syncthreads();

        // ---- compute: wave handles 8 edges, lane handles channels {lane, lane+64} ----
        float acc0[8], acc1[8];
        #pragma unroll
        for (int t = 0; t < 8; ++t) { acc0[t] = sB1[lane]; acc1[t] = sB1[lane + 64]; }
        const int eb = wave * 8;

        #pragma unroll 4
        for (int c = 0; c < 32; ++c) {
            float w0[4], w1[4];
            #pragma unroll
            for (int r = 0; r < 4; ++r) {
                w0[r] = sW1[(4 * c + r) * 128 + lane];        // conflict-free (2 lanes/bank)
                w1[r] = sW1[(4 * c + r) * 128 + lane + 64];
            }
            #pragma unroll
            for (int t = 0; t < 8; ++t) {
                float4 xv = *(const float4*)(&sX[eb + t][4 * c]);  // LDS broadcast
                acc0[t] = fmaf(xv.x, w0[0], acc0[t]);
                acc0[t] = fmaf(xv.y, w0[1], acc0[t]);
                acc0[t] = fmaf(xv.z, w0[2], acc0[t]);
                acc0[t] = fmaf(xv.w, w0[3], acc0[t]);
                acc1[t] = fmaf(xv.x, w1[0], acc1[t]);
                acc1[t] = fmaf(xv.y, w1[1], acc1[t]);
                acc1[t] = fmaf(xv.z, w1[2], acc1[t]);
                acc1[t] = fmaf(xv.w, w1[3], acc1[t]);
            }
        }

        // ---- relu, dot with W2, wave-reduce, store ----
        #pragma unroll
        for (int t = 0; t < 8; ++t) {
            float p = fmaxf(acc0[t], 0.f) * sW2[lane]
                    + fmaxf(acc1[t], 0.f) * sW2[lane + 64];
            #pragma unroll
            for (int off = 32; off > 0; off >>= 1)
                p += __shfl_xor(p, off, 64);
            const int eo = e0 + eb + t;
            if (lane == 0 && eo < nE) out[eo] = p + bias2;
        }
        __syncthreads();   // before next tile overwrites sX
    }
}

extern "C" void kernel_launch(void* const* d_in, const int* in_sizes, int n_in,
                              void* d_out, int out_size, void* d_ws, size_t ws_size,
                              hipStream_t stream) {
    const float* z  = (const float*)d_in[0];
    const void*  edge = d_in[1];
    const float* W1 = (const float*)d_in[2];
    const float* b1 = (const float*)d_in[3];
    const float* W2 = (const float*)d_in[4];
    const float* b2 = (const float*)d_in[5];
    float* out = (float*)d_out;
    const int nE = out_size;

    const int grid = 256;  // 1 block/CU (LDS-limited: 99 KiB/block)
    edge_mlp_f32<<<grid, THREADS, 0, stream>>>(z, edge, W1, b1, W2, b2, out, nE);
}

// Round 3
// 357.880 us; speedup vs baseline: 1.6703x; 1.6703x over previous
//
#include <hip/hip_runtime.h>
#include <hip/hip_bf16.h>

typedef __attribute__((ext_vector_type(8))) short bf16x8;  // 8 bf16 = 4 VGPRs
typedef __attribute__((ext_vector_type(4))) float f32x4;

#define THREADS 512
#define TILE_E 128   // 8 waves x 16 edges

static __device__ __forceinline__ short f2bf(float f) {
    __hip_bfloat16 h = __float2bfloat16(f);   // RNE
    return *reinterpret_cast<short*>(&h);
}

// out[e] = relu((z[a]*z[b]) @ W1 + b1) @ W2 + b2   via bf16 MFMA
__global__ __launch_bounds__(THREADS, 4) void edge_mlp_mfma(
    const float* __restrict__ z,
    const void* __restrict__ edge,   // int32 or int64 (detected)
    const float* __restrict__ W1,    // [128 in][128 hid] row-major
    const float* __restrict__ b1,
    const float* __restrict__ W2,
    const float* __restrict__ b2,
    float* __restrict__ out,
    int nE)
{
    __shared__ short sW1t[128 * 128];  // bf16 [n][k]; in-row bytes ^= (n&7)<<4 (32 KiB)
    __shared__ int   sI64;

    // ---- stage W1 -> bf16, transposed to [n][k], swizzled ----
    for (int c = threadIdx.x; c < 128 * 32; c += THREADS) {
        const int k = c >> 5, n4 = (c & 31) << 2;
        float4 w = *(const float4*)(W1 + k * 128 + n4);   // W1[k][n4..n4+4)
        #pragma unroll
        for (int u = 0; u < 4; ++u) {
            const int n = n4 + u;
            const unsigned addr = (unsigned)(n * 256)
                                + (((unsigned)(k * 2)) ^ ((unsigned)(n & 7) << 4));
            *(short*)((char*)sW1t + addr) = f2bf((&w.x)[u]);
        }
    }
    if (threadIdx.x < 64) {  // detect int64 indices: all odd words zero
        unsigned v = ((const unsigned*)edge)[2 * threadIdx.x + 1];
        unsigned long long nz = __ballot(v != 0u);
        if (threadIdx.x == 0) sI64 = (nz == 0ull) ? 1 : 0;
    }
    __syncthreads();
    const int i64 = sI64;
    const int* e32 = (const int*)edge;

    const int wave = threadIdx.x >> 6;
    const int lane = threadIdx.x & 63;
    const int col  = lane & 15;       // MFMA A-row / D-col selector
    const int hi   = lane >> 4;       // k-group

    // per-lane constants
    const float bias2 = b2[0];
    float w2v[8], bini[8];
    #pragma unroll
    for (int nt = 0; nt < 8; ++nt) {
        w2v[nt]  = W2[nt * 16 + col];
        bini[nt] = b1[nt * 16 + col];
    }
    // B-fragment address: n = nt*16+col, in-row k-offset = (kt*64 + hi*16) ^ ((col&7)<<4)
    const unsigned mask = ((unsigned)(col & 7)) << 4;
    const unsigned rowB = (unsigned)(col * 256);
    unsigned kxor[4];
    #pragma unroll
    for (int kt = 0; kt < 4; ++kt)
        kxor[kt] = ((unsigned)(kt * 64 + hi * 16)) ^ mask;

    const int nTiles = (nE + TILE_E - 1) / TILE_E;
    for (int tile = blockIdx.x; tile < nTiles; tile += gridDim.x) {
        const int e0 = tile * TILE_E;
        const int eRow = e0 + (wave << 4) + col;           // this lane's edge (A-row)
        const int eC = eRow < nE ? eRow : nE - 1;

        const int aIdx = i64 ? e32[2 * eC]        : e32[eC];
        const int bIdx = i64 ? e32[2 * (nE + eC)] : e32[nE + eC];
        const float* za = z + (long)aIdx * 128 + hi * 8;
        const float* zb = z + (long)bIdx * 128 + hi * 8;

        f32x4 acc[8];
        #pragma unroll
        for (int nt = 0; nt < 8; ++nt) {
            acc[nt][0] = bini[nt]; acc[nt][1] = bini[nt];
            acc[nt][2] = bini[nt]; acc[nt][3] = bini[nt];
        }

        #pragma unroll
        for (int kt = 0; kt < 4; ++kt) {
            // A-fragment: 8 channels of z[a]*z[b] at k = kt*32 + hi*8 + j
            float4 a0 = *(const float4*)(za + kt * 32);
            float4 a1 = *(const float4*)(za + kt * 32 + 4);
            float4 c0 = *(const float4*)(zb + kt * 32);
            float4 c1 = *(const float4*)(zb + kt * 32 + 4);
            bf16x8 af;
            af[0] = f2bf(a0.x * c0.x); af[1] = f2bf(a0.y * c0.y);
            af[2] = f2bf(a0.z * c0.z); af[3] = f2bf(a0.w * c0.w);
            af[4] = f2bf(a1.x * c1.x); af[5] = f2bf(a1.y * c1.y);
            af[6] = f2bf(a1.z * c1.z); af[7] = f2bf(a1.w * c1.w);

            #pragma unroll
            for (int nt = 0; nt < 8; ++nt) {
                bf16x8 bf = *(const bf16x8*)((const char*)sW1t
                              + rowB + (unsigned)nt * 4096 + kxor[kt]);
                acc[nt] = __builtin_amdgcn_mfma_f32_16x16x32_bf16(af, bf, acc[nt], 0, 0, 0);
            }
        }

        // ---- epilogue: relu, dot W2, reduce 16 cols, store ----
        #pragma unroll
        for (int r = 0; r < 4; ++r) {
            float s = 0.f;
            #pragma unroll
            for (int nt = 0; nt < 8; ++nt)
                s = fmaf(fmaxf(acc[nt][r], 0.f), w2v[nt], s);
            s += __shfl_xor(s, 1, 64);
            s += __shfl_xor(s, 2, 64);
            s += __shfl_xor(s, 4, 64);
            s += __shfl_xor(s, 8, 64);
            const int eo = e0 + (wave << 4) + (hi << 2) + r;  // D: row=(lane>>4)*4+r
            if (col == 0 && eo < nE) out[eo] = s + bias2;
        }
    }
}

extern "C" void kernel_launch(void* const* d_in, const int* in_sizes, int n_in,
                              void* d_out, int out_size, void* d_ws, size_t ws_size,
                              hipStream_t stream) {
    const float* z  = (const float*)d_in[0];
    const void* edge = d_in[1];
    const float* W1 = (const float*)d_in[2];
    const float* b1 = (const float*)d_in[3];
    const float* W2 = (const float*)d_in[4];
    const float* b2 = (const float*)d_in[5];
    float* out = (float*)d_out;
    const int nE = out_size;

    edge_mlp_mfma<<<512, THREADS, 0, stream>>>(z, edge, W1, b1, W2, b2, out, nE);
}

// Round 4
// 341.386 us; speedup vs baseline: 1.7510x; 1.0483x over previous
//
#include <hip/hip_runtime.h>
#include <hip/hip_bf16.h>

typedef __attribute__((ext_vector_type(8))) short bf16x8;  // 8 bf16 = 4 VGPRs
typedef __attribute__((ext_vector_type(4))) short short4v;
typedef __attribute__((ext_vector_type(4))) float f32x4;

#define THREADS 512
#define TILE_E 128   // 8 waves x 16 edges

static __device__ __forceinline__ short f2bf(float f) {
    __hip_bfloat16 h = __float2bfloat16(f);   // RNE
    return *reinterpret_cast<short*>(&h);
}
static __device__ __forceinline__ float bf2f(short s) {
    unsigned u = ((unsigned)(unsigned short)s) << 16;
    return __builtin_bit_cast(float, u);
}

// pre-pass: z (f32) -> zb (bf16), halves gather traffic
__global__ void z_to_bf16(const float* __restrict__ z, short* __restrict__ zb, int n4) {
    int i = blockIdx.x * blockDim.x + threadIdx.x;
    const int stride = gridDim.x * blockDim.x;
    for (; i < n4; i += stride) {
        float4 v = ((const float4*)z)[i];
        short4v o;
        o[0] = f2bf(v.x); o[1] = f2bf(v.y); o[2] = f2bf(v.z); o[3] = f2bf(v.w);
        ((short4v*)zb)[i] = o;
    }
}

// out[e] = relu((z[a]*z[b]) @ W1 + b1) @ W2 + b2   via bf16 MFMA
template<bool BF16Z>
__global__ __launch_bounds__(THREADS, 4) void edge_mlp_mfma(
    const float* __restrict__ z,
    const short* __restrict__ zb,    // bf16 z (used when BF16Z)
    const void* __restrict__ edge,   // int32 or int64 (detected)
    const float* __restrict__ W1,    // [128 in][128 hid] row-major
    const float* __restrict__ b1,
    const float* __restrict__ W2,
    const float* __restrict__ b2,
    float* __restrict__ out,
    int nE)
{
    __shared__ short sW1t[128 * 128];  // bf16 [n][k]; in-row bytes ^= (n&7)<<4 (32 KiB)
    __shared__ int   sI64;

    // ---- stage W1 -> bf16, transposed to [n][k], swizzled ----
    for (int c = threadIdx.x; c < 128 * 32; c += THREADS) {
        const int k = c >> 5, n4 = (c & 31) << 2;
        float4 w = *(const float4*)(W1 + k * 128 + n4);   // W1[k][n4..n4+4)
        #pragma unroll
        for (int u = 0; u < 4; ++u) {
            const int n = n4 + u;
            const unsigned addr = (unsigned)(n * 256)
                                + (((unsigned)(k * 2)) ^ ((unsigned)(n & 7) << 4));
            *(short*)((char*)sW1t + addr) = f2bf((&w.x)[u]);
        }
    }
    if (threadIdx.x < 64) {  // detect int64 indices: all odd words zero
        unsigned v = ((const unsigned*)edge)[2 * threadIdx.x + 1];
        unsigned long long nz = __ballot(v != 0u);
        if (threadIdx.x == 0) sI64 = (nz == 0ull) ? 1 : 0;
    }
    __syncthreads();
    const int i64 = sI64;
    const int* e32 = (const int*)edge;

    const int wave = threadIdx.x >> 6;
    const int lane = threadIdx.x & 63;
    const int col  = lane & 15;       // MFMA A-row / D-col selector
    const int hi   = lane >> 4;       // k-group

    const float bias2 = b2[0];
    float w2v[8], bini[8];
    #pragma unroll
    for (int nt = 0; nt < 8; ++nt) {
        w2v[nt]  = W2[nt * 16 + col];
        bini[nt] = b1[nt * 16 + col];
    }
    // B-fragment address: n = nt*16+col, in-row k-offset = (kt*64 + hi*16) ^ ((col&7)<<4)
    const unsigned mask = ((unsigned)(col & 7)) << 4;
    const unsigned rowB = (unsigned)(col * 256);
    unsigned kxor[4];
    #pragma unroll
    for (int kt = 0; kt < 4; ++kt)
        kxor[kt] = ((unsigned)(kt * 64 + hi * 16)) ^ mask;

    const int nTiles = (nE + TILE_E - 1) / TILE_E;
    for (int tile = blockIdx.x; tile < nTiles; tile += gridDim.x) {
        const int e0 = tile * TILE_E;
        const int eRow = e0 + (wave << 4) + col;           // this lane's edge (A-row)
        const int eC = eRow < nE ? eRow : nE - 1;

        const int aIdx = i64 ? e32[2 * eC]        : e32[eC];
        const int bIdx = i64 ? e32[2 * (nE + eC)] : e32[nE + eC];

        f32x4 acc[8];
        #pragma unroll
        for (int nt = 0; nt < 8; ++nt) {
            acc[nt][0] = bini[nt]; acc[nt][1] = bini[nt];
            acc[nt][2] = bini[nt]; acc[nt][3] = bini[nt];
        }

        #pragma unroll
        for (int kt = 0; kt < 4; ++kt) {
            bf16x8 af;
            if (BF16Z) {
                const short* pa = zb + (long)aIdx * 128 + hi * 8 + kt * 32;
                const short* pb = zb + (long)bIdx * 128 + hi * 8 + kt * 32;
                bf16x8 av = *(const bf16x8*)pa;            // 16 B
                bf16x8 bv = *(const bf16x8*)pb;
                #pragma unroll
                for (int j = 0; j < 8; ++j)
                    af[j] = f2bf(bf2f(av[j]) * bf2f(bv[j]));
            } else {
                const float* pa = z + (long)aIdx * 128 + hi * 8 + kt * 32;
                const float* pb = z + (long)bIdx * 128 + hi * 8 + kt * 32;
                float4 a0 = *(const float4*)pa;
                float4 a1 = *(const float4*)(pa + 4);
                float4 c0 = *(const float4*)pb;
                float4 c1 = *(const float4*)(pb + 4);
                af[0] = f2bf(a0.x * c0.x); af[1] = f2bf(a0.y * c0.y);
                af[2] = f2bf(a0.z * c0.z); af[3] = f2bf(a0.w * c0.w);
                af[4] = f2bf(a1.x * c1.x); af[5] = f2bf(a1.y * c1.y);
                af[6] = f2bf(a1.z * c1.z); af[7] = f2bf(a1.w * c1.w);
            }

            #pragma unroll
            for (int nt = 0; nt < 8; ++nt) {
                bf16x8 bf = *(const bf16x8*)((const char*)sW1t
                              + rowB + (unsigned)nt * 4096 + kxor[kt]);
                acc[nt] = __builtin_amdgcn_mfma_f32_16x16x32_bf16(af, bf, acc[nt], 0, 0, 0);
            }
        }

        // ---- epilogue: relu, dot W2, reduce 16 cols, store ----
        #pragma unroll
        for (int r = 0; r < 4; ++r) {
            float s = 0.f;
            #pragma unroll
            for (int nt = 0; nt < 8; ++nt)
                s = fmaf(fmaxf(acc[nt][r], 0.f), w2v[nt], s);
            s += __shfl_xor(s, 1, 64);
            s += __shfl_xor(s, 2, 64);
            s += __shfl_xor(s, 4, 64);
            s += __shfl_xor(s, 8, 64);
            const int eo = e0 + (wave << 4) + (hi << 2) + r;  // D: row=(lane>>4)*4+r
            if (col == 0 && eo < nE) out[eo] = s + bias2;
        }
    }
}

extern "C" void kernel_launch(void* const* d_in, const int* in_sizes, int n_in,
                              void* d_out, int out_size, void* d_ws, size_t ws_size,
                              hipStream_t stream) {
    const float* z  = (const float*)d_in[0];
    const void* edge = d_in[1];
    const float* W1 = (const float*)d_in[2];
    const float* b1 = (const float*)d_in[3];
    const float* W2 = (const float*)d_in[4];
    const float* b2 = (const float*)d_in[5];
    float* out = (float*)d_out;
    const int nE = out_size;
    const int nZ = in_sizes[0];                    // 100000*128

    const bool useBf = ws_size >= (size_t)nZ * 2;  // constant across calls -> graph-safe
    if (useBf) {
        short* zbf = (short*)d_ws;
        z_to_bf16<<<1024, 256, 0, stream>>>(z, zbf, nZ / 4);
        edge_mlp_mfma<true><<<1024, THREADS, 0, stream>>>(
            z, zbf, edge, W1, b1, W2, b2, out, nE);
    } else {
        edge_mlp_mfma<false><<<1024, THREADS, 0, stream>>>(
            z, nullptr, edge, W1, b1, W2, b2, out, nE);
    }
}

// Round 5
// 154.099 us; speedup vs baseline: 3.8792x; 2.2154x over previous
//
#include <hip/hip_runtime.h>
#include <hip/hip_bf16.h>

typedef __attribute__((ext_vector_type(8))) short bf16x8;  // 8 bf16 = 4 VGPRs
typedef __attribute__((ext_vector_type(4))) short short4v;
typedef __attribute__((ext_vector_type(4))) float f32x4;

#define THREADS 512
#define TILE_E 128   // 8 waves x 16 edges

static __device__ __forceinline__ short f2bf(float f) {
    __hip_bfloat16 h = __float2bfloat16(f);   // RNE
    return *reinterpret_cast<short*>(&h);
}
static __device__ __forceinline__ float bf2f(short s) {
    unsigned u = ((unsigned)(unsigned short)s) << 16;
    return __builtin_bit_cast(float, u);
}

// pre-pass: z (f32) -> zb (bf16), halves gather traffic
__global__ void z_to_bf16(const float* __restrict__ z, short* __restrict__ zb, int n4) {
    int i = blockIdx.x * blockDim.x + threadIdx.x;
    const int stride = gridDim.x * blockDim.x;
    for (; i < n4; i += stride) {
        float4 v = ((const float4*)z)[i];
        short4v o;
        o[0] = f2bf(v.x); o[1] = f2bf(v.y); o[2] = f2bf(v.z); o[3] = f2bf(v.w);
        ((short4v*)zb)[i] = o;
    }
}

// out[e] = relu((z[a]*z[b]) @ W1 + b1) @ W2 + b2   via bf16 MFMA
// NOTE: __launch_bounds__ 2nd arg empirically acts as blocks/CU here:
// (512,4) capped VGPR at 64 -> ~400 B/thread scratch spill (R4: WRITE_SIZE 213MB).
// (512,2) -> cap 128, no spill (R1: VGPR=116, WRITE == out size exactly).
template<bool BF16Z>
__global__ __launch_bounds__(THREADS, 2) void edge_mlp_mfma(
    const float* __restrict__ z,
    const short* __restrict__ zb,    // bf16 z (used when BF16Z)
    const void* __restrict__ edge,   // int32 or int64 (detected)
    const float* __restrict__ W1,    // [128 in][128 hid] row-major
    const float* __restrict__ b1,
    const float* __restrict__ W2,
    const float* __restrict__ b2,
    float* __restrict__ out,
    int nE)
{
    __shared__ short sW1t[128 * 128];  // bf16 [n][k]; in-row bytes ^= (n&7)<<4 (32 KiB)
    __shared__ int   sI64;

    // ---- stage W1 -> bf16 [n][k] swizzled; lane owns (n, k4): 4 consecutive k ----
    // global: for fixed (k4,i), 128 consecutive-n lanes read consecutive floats (coalesced)
    // LDS: one 8B write per (n,k4), ~4-way banked instead of 32-way
    for (int c = threadIdx.x; c < 128 * 32; c += THREADS) {
        const int n = c & 127, k4 = c >> 7;   // k = 4*k4 .. 4*k4+3
        short4v w;
        #pragma unroll
        for (int i = 0; i < 4; ++i)
            w[i] = f2bf(W1[(4 * k4 + i) * 128 + n]);
        const unsigned addr = (unsigned)(n * 256)
                            + (((unsigned)(k4 * 8)) ^ ((unsigned)(n & 7) << 4));
        *(short4v*)((char*)sW1t + addr) = w;
    }
    if (threadIdx.x < 64) {  // detect int64 indices: all odd words zero
        unsigned v = ((const unsigned*)edge)[2 * threadIdx.x + 1];
        unsigned long long nz = __ballot(v != 0u);
        if (threadIdx.x == 0) sI64 = (nz == 0ull) ? 1 : 0;
    }
    __syncthreads();
    const int i64 = sI64;
    const int* e32 = (const int*)edge;

    const int wave = threadIdx.x >> 6;
    const int lane = threadIdx.x & 63;
    const int col  = lane & 15;       // MFMA A-row / D-col selector
    const int hi   = lane >> 4;       // k-group

    const float bias2 = b2[0];
    float w2v[8], bini[8];
    #pragma unroll
    for (int nt = 0; nt < 8; ++nt) {
        w2v[nt]  = W2[nt * 16 + col];
        bini[nt] = b1[nt * 16 + col];
    }
    // B-fragment address: n = nt*16+col, in-row k-offset = (kt*64 + hi*16) ^ ((col&7)<<4)
    const unsigned mask = ((unsigned)(col & 7)) << 4;
    const unsigned rowB = (unsigned)(col * 256);
    unsigned kxor[4];
    #pragma unroll
    for (int kt = 0; kt < 4; ++kt)
        kxor[kt] = ((unsigned)(kt * 64 + hi * 16)) ^ mask;

    const int nTiles = (nE + TILE_E - 1) / TILE_E;
    for (int tile = blockIdx.x; tile < nTiles; tile += gridDim.x) {
        const int e0 = tile * TILE_E;
        const int eRow = e0 + (wave << 4) + col;           // this lane's edge (A-row)
        const int eC = eRow < nE ? eRow : nE - 1;

        const int aIdx = i64 ? e32[2 * eC]        : e32[eC];
        const int bIdx = i64 ? e32[2 * (nE + eC)] : e32[nE + eC];

        f32x4 acc[8];
        #pragma unroll
        for (int nt = 0; nt < 8; ++nt) {
            acc[nt][0] = bini[nt]; acc[nt][1] = bini[nt];
            acc[nt][2] = bini[nt]; acc[nt][3] = bini[nt];
        }

        if (BF16Z) {
            // issue all 8 gather loads first (8 x 16B in flight per lane)
            const short* pa = zb + (long)aIdx * 128 + hi * 8;
            const short* pb = zb + (long)bIdx * 128 + hi * 8;
            bf16x8 av0 = *(const bf16x8*)(pa);
            bf16x8 av1 = *(const bf16x8*)(pa + 32);
            bf16x8 av2 = *(const bf16x8*)(pa + 64);
            bf16x8 av3 = *(const bf16x8*)(pa + 96);
            bf16x8 bv0 = *(const bf16x8*)(pb);
            bf16x8 bv1 = *(const bf16x8*)(pb + 32);
            bf16x8 bv2 = *(const bf16x8*)(pb + 64);
            bf16x8 bv3 = *(const bf16x8*)(pb + 96);
            bf16x8 avs[4] = {av0, av1, av2, av3};
            bf16x8 bvs[4] = {bv0, bv1, bv2, bv3};
            #pragma unroll
            for (int kt = 0; kt < 4; ++kt) {
                bf16x8 af;
                #pragma unroll
                for (int j = 0; j < 8; ++j)
                    af[j] = f2bf(bf2f(avs[kt][j]) * bf2f(bvs[kt][j]));
                #pragma unroll
                for (int nt = 0; nt < 8; ++nt) {
                    bf16x8 bf = *(const bf16x8*)((const char*)sW1t
                                  + rowB + (unsigned)nt * 4096 + kxor[kt]);
                    acc[nt] = __builtin_amdgcn_mfma_f32_16x16x32_bf16(af, bf, acc[nt], 0, 0, 0);
                }
            }
        } else {
            const float* pa = z + (long)aIdx * 128 + hi * 8;
            const float* pb = z + (long)bIdx * 128 + hi * 8;
            #pragma unroll
            for (int kt = 0; kt < 4; ++kt) {
                float4 a0 = *(const float4*)(pa + kt * 32);
                float4 a1 = *(const float4*)(pa + kt * 32 + 4);
                float4 c0 = *(const float4*)(pb + kt * 32);
                float4 c1 = *(const float4*)(pb + kt * 32 + 4);
                bf16x8 af;
                af[0] = f2bf(a0.x * c0.x); af[1] = f2bf(a0.y * c0.y);
                af[2] = f2bf(a0.z * c0.z); af[3] = f2bf(a0.w * c0.w);
                af[4] = f2bf(a1.x * c1.x); af[5] = f2bf(a1.y * c1.y);
                af[6] = f2bf(a1.z * c1.z); af[7] = f2bf(a1.w * c1.w);
                #pragma unroll
                for (int nt = 0; nt < 8; ++nt) {
                    bf16x8 bf = *(const bf16x8*)((const char*)sW1t
                                  + rowB + (unsigned)nt * 4096 + kxor[kt]);
                    acc[nt] = __builtin_amdgcn_mfma_f32_16x16x32_bf16(af, bf, acc[nt], 0, 0, 0);
                }
            }
        }

        // ---- epilogue: relu, dot W2, reduce 16 cols, store ----
        #pragma unroll
        for (int r = 0; r < 4; ++r) {
            float s = 0.f;
            #pragma unroll
            for (int nt = 0; nt < 8; ++nt)
                s = fmaf(fmaxf(acc[nt][r], 0.f), w2v[nt], s);
            s += __shfl_xor(s, 1, 64);
            s += __shfl_xor(s, 2, 64);
            s += __shfl_xor(s, 4, 64);
            s += __shfl_xor(s, 8, 64);
            const int eo = e0 + (wave << 4) + (hi << 2) + r;  // D: row=(lane>>4)*4+r
            if (col == 0 && eo < nE) out[eo] = s + bias2;
        }
    }
}

extern "C" void kernel_launch(void* const* d_in, const int* in_sizes, int n_in,
                              void* d_out, int out_size, void* d_ws, size_t ws_size,
                              hipStream_t stream) {
    const float* z  = (const float*)d_in[0];
    const void* edge = d_in[1];
    const float* W1 = (const float*)d_in[2];
    const float* b1 = (const float*)d_in[3];
    const float* W2 = (const float*)d_in[4];
    const float* b2 = (const float*)d_in[5];
    float* out = (float*)d_out;
    const int nE = out_size;
    const int nZ = in_sizes[0];                    // 100000*128

    const bool useBf = ws_size >= (size_t)nZ * 2;  // constant across calls -> graph-safe
    if (useBf) {
        short* zbf = (short*)d_ws;
        z_to_bf16<<<1024, 256, 0, stream>>>(z, zbf, nZ / 4);
        edge_mlp_mfma<true><<<512, THREADS, 0, stream>>>(
            z, zbf, edge, W1, b1, W2, b2, out, nE);
    } else {
        edge_mlp_mfma<false><<<512, THREADS, 0, stream>>>(
            z, nullptr, edge, W1, b1, W2, b2, out, nE);
    }
}